// Round 4
// baseline (680.920 us; speedup 1.0000x reference)
//
#include <hip/hip_runtime.h>

#define BLK 256
#define TILE1 8192
#define IPT1 32
#define K1CAP 1280        // idx-bucket stream cap: mean 1024, sd 32 (+8 sigma)
#define CAPB 9216         // dst-bucket stream cap: mean 8192, sd 90 (+11 sigma)
#define MAXNBI 2048
#define MAXS2 1024        // 4 * max dst-buckets
#define OVFN 65536

// ---------------- init: copy compact x (n,10) into strided h (n,16) --------
__global__ void k_init_h(const float* __restrict__ x, float* __restrict__ h, int n) {
    int total = n * 16;
    int gs = gridDim.x * blockDim.x;
    for (int i = blockIdx.x * blockDim.x + threadIdx.x; i < total; i += gs) {
        int row = i >> 4, col = i & 15;
        h[i] = (col < 10) ? x[row * 10 + col] : 0.0f;
    }
}

// ---------------- bin1: bucket order entries by idx>>12 (no gather) --------
__global__ __launch_bounds__(256) void k_bin1(const int* __restrict__ orders, int epo,
                                              int NBI, int tps,
                                              int* __restrict__ gcnt1, int* __restrict__ recs1,
                                              int* __restrict__ ovf1_cnt, int* __restrict__ ovf1) {
    __shared__ int bcnt[MAXNBI];
    __shared__ int gbase[MAXNBI];
    int t = threadIdx.x;
    int st = blockIdx.x / tps;
    int tb = blockIdx.x % tps;
    for (int i = t; i < NBI; i += 256) bcnt[i] = 0;
    __syncthreads();

    int base = tb * TILE1;
    int idxr[IPT1];
    int rr[IPT1];
    #pragma unroll
    for (int q = 0; q < IPT1; ++q) {
        int e = base + q * 256 + t;
        int idx = -1, r = 0;
        if (e < epo) {
            idx = orders[(size_t)st * epo + e];
            r = atomicAdd(&bcnt[idx >> 12], 1);
        }
        idxr[q] = idx; rr[q] = r;
    }
    __syncthreads();
    for (int k = t; k < NBI; k += 256) {
        int c = bcnt[k];
        gbase[k] = (c > 0) ? atomicAdd(&gcnt1[st * NBI + k], c) : 0;
    }
    __syncthreads();
    #pragma unroll
    for (int q = 0; q < IPT1; ++q) {
        int idx = idxr[q];
        if (idx >= 0) {
            int key = idx >> 12;
            int pos = gbase[key] + rr[q];
            if (pos < K1CAP) {
                recs1[((size_t)st * NBI + key) * K1CAP + pos] = idx;
            } else {
                int o = atomicAdd(ovf1_cnt, 1);
                if (o < OVFN) ovf1[o] = (st << 23) | idx;   // idx < 2^23
            }
        }
    }
}

// ---------------- bin2: resolve (d,s) in L2 window, re-bin by dst>>9 -------
__global__ __launch_bounds__(256) void k_bin2(const int* __restrict__ ei, int ne,
                                              const int* __restrict__ gcnt1,
                                              const int* __restrict__ recs1,
                                              int NBI, int NBD,
                                              int* __restrict__ gcnt2, unsigned* __restrict__ recs2,
                                              int* __restrict__ ovf2_cnt, int2* __restrict__ ovf2) {
    __shared__ int bcnt[MAXS2];
    __shared__ int gbase[MAXS2];
    int t = threadIdx.x;
    int ib = blockIdx.x;
    int S2 = 4 * NBD;
    for (int i = t; i < S2; i += 256) bcnt[i] = 0;
    __syncthreads();

    unsigned recr[4][5];
    int metar[4][5];
    #pragma unroll
    for (int st = 0; st < 4; ++st) {
        int cnt = gcnt1[st * NBI + ib];
        if (cnt > K1CAP) cnt = K1CAP;
        const int* strm = recs1 + ((size_t)st * NBI + ib) * K1CAP;
        #pragma unroll
        for (int q = 0; q < 5; ++q) {
            int r = q * 256 + t;
            unsigned rec = 0u; int meta = -1;
            if (r < cnt) {
                int idx = strm[r];
                int d = ei[idx];                    // 16KB window, L2-hot
                int s = ei[(size_t)ne + idx];       // 16KB window, L2-hot
                rec = ((unsigned)(d & 511) << 20) | (unsigned)s;  // s < 2^20
                int key = st * NBD + (d >> 9);
                int rk = atomicAdd(&bcnt[key], 1);  // rk < 5120 fits 13 bits
                meta = (key << 13) | rk;
            }
            recr[st][q] = rec; metar[st][q] = meta;
        }
    }
    __syncthreads();
    for (int k = t; k < S2; k += 256) {
        int c = bcnt[k];
        gbase[k] = (c > 0) ? atomicAdd(&gcnt2[k], c) : 0;
    }
    __syncthreads();
    #pragma unroll
    for (int st = 0; st < 4; ++st) {
        #pragma unroll
        for (int q = 0; q < 5; ++q) {
            int meta = metar[st][q];
            if (meta >= 0) {
                int key = meta >> 13, rk = meta & 8191;
                int pos = gbase[key] + rk;
                if (pos < CAPB) {
                    recs2[(size_t)key * CAPB + pos] = recr[st][q];
                } else {
                    int o = atomicAdd(ovf2_cnt, 1);
                    if (o < OVFN) {
                        int d_global = (key % NBD) * 512 + (int)(recr[st][q] >> 20);
                        int stt = key / NBD;
                        ovf2[o] = make_int2((stt << 18) | d_global,
                                            (int)(recr[st][q] & 0xFFFFFu));
                    }
                }
            }
        }
    }
}

// ---------------- aggregate one step: LDS accumulators, no global atomics --
__global__ __launch_bounds__(256) void k_agg(const float* __restrict__ h_cur,
                                             float* __restrict__ h_next,
                                             const int* __restrict__ gcnt2_st,
                                             const unsigned* __restrict__ recs2_st,
                                             const float* __restrict__ w_mp,
                                             const float* __restrict__ b_mp, int n) {
    __shared__ float acc[256 * 10];
    __shared__ int   degs[256];
    __shared__ float Wa[100], Wb[100], Bm[10];
    int t = threadIdx.x;
    if (t < 100) {
        int k = t / 10, j = t - k * 10;
        float w1 = w_mp[k * 20 + j];
        float w2 = w_mp[k * 20 + 10 + j];
        Wa[t] = w1 - w2; Wb[t] = w2;
    }
    if (t < 10) Bm[t] = b_mp[t];
    #pragma unroll
    for (int q = 0; q < 10; ++q) acc[q * 256 + t] = 0.0f;
    degs[t] = 0;
    __syncthreads();

    int dbkt = blockIdx.x >> 1, half = blockIdx.x & 1;
    int cnt = gcnt2_st[dbkt];
    if (cnt > CAPB) cnt = CAPB;
    const unsigned* strm = recs2_st + (size_t)dbkt * CAPB;

    for (int r = t; r < cnt; r += 256) {
        unsigned rec = strm[r];
        int dl = (int)(rec >> 20);
        if ((dl >> 8) == half) {
            int s = (int)(rec & 0xFFFFFu);
            const float* pj = h_cur + (size_t)s * 16;
            float4 a0 = *(const float4*)(pj);
            float4 a1 = *(const float4*)(pj + 4);
            float2 a2 = *(const float2*)(pj + 8);
            float* a = &acc[(dl & 255) * 10];
            atomicAdd(a + 0, a0.x); atomicAdd(a + 1, a0.y);
            atomicAdd(a + 2, a0.z); atomicAdd(a + 3, a0.w);
            atomicAdd(a + 4, a1.x); atomicAdd(a + 5, a1.y);
            atomicAdd(a + 6, a1.z); atomicAdd(a + 7, a1.w);
            atomicAdd(a + 8, a2.x); atomicAdd(a + 9, a2.y);
            atomicAdd(&degs[dl & 255], 1);
        }
    }
    __syncthreads();

    int i = dbkt * 512 + half * 256 + t;
    if (i >= n) return;
    const float* pi = h_cur + (size_t)i * 16;
    float4 x0 = *(const float4*)(pi);
    float4 x1 = *(const float4*)(pi + 4);
    float2 x2 = *(const float2*)(pi + 8);
    float xi[10] = {x0.x, x0.y, x0.z, x0.w, x1.x, x1.y, x1.z, x1.w, x2.x, x2.y};
    float S[10];
    #pragma unroll
    for (int q = 0; q < 10; ++q) S[q] = acc[t * 10 + q];
    float deg = (float)degs[t];

    float o[10];
    #pragma unroll
    for (int k = 0; k < 10; ++k) {
        float ma = Bm[k];
        float mb = 0.0f;
        #pragma unroll
        for (int j = 0; j < 10; ++j) {
            ma += Wa[k * 10 + j] * xi[j];
            mb += Wb[k * 10 + j] * S[j];
        }
        o[k] = xi[k] + deg * ma + mb;
    }
    float* po = h_next + (size_t)i * 16;
    *(float4*)(po)     = make_float4(o[0], o[1], o[2], o[3]);
    *(float4*)(po + 4) = make_float4(o[4], o[5], o[6], o[7]);
    *(float2*)(po + 8) = make_float2(o[8], o[9]);
}

// ---------------- overflow fix-up (expected zero entries) -------------------
__global__ void k_fix(const float* __restrict__ h_cur, float* __restrict__ h_next,
                      const int* __restrict__ ei, int ne,
                      const int* __restrict__ ovf1_cnt, const int* __restrict__ ovf1,
                      const int* __restrict__ ovf2_cnt, const int2* __restrict__ ovf2,
                      const float* __restrict__ w_mp, const float* __restrict__ b_mp, int st) {
    __shared__ float Wa[100], Wb[100], Bm[10];
    int t = threadIdx.x;
    if (t < 100) {
        int k = t / 10, j = t - k * 10;
        float w1 = w_mp[k * 20 + j];
        float w2 = w_mp[k * 20 + 10 + j];
        Wa[t] = w1 - w2; Wb[t] = w2;
    }
    if (t < 10) Bm[t] = b_mp[t];
    __syncthreads();
    int c1 = *ovf1_cnt; if (c1 > OVFN) c1 = OVFN;
    int c2 = *ovf2_cnt; if (c2 > OVFN) c2 = OVFN;
    int gs = gridDim.x * blockDim.x;
    int g = blockIdx.x * blockDim.x + t;
    for (int i = g; i < c1 + c2; i += gs) {
        int d, s;
        if (i < c1) {
            int v = ovf1[i];
            if ((v >> 23) != st) continue;
            int idx = v & 0x7FFFFF;
            d = ei[idx]; s = ei[(size_t)ne + idx];
        } else {
            int2 p = ovf2[i - c1];
            if ((p.x >> 18) != st) continue;
            d = p.x & 0x3FFFF; s = p.y;
        }
        const float* pi = h_cur + (size_t)d * 16;
        const float* pj = h_cur + (size_t)s * 16;
        float xi[10], xj[10];
        #pragma unroll
        for (int j = 0; j < 10; ++j) { xi[j] = pi[j]; xj[j] = pj[j]; }
        float* po = h_next + (size_t)d * 16;
        #pragma unroll
        for (int k = 0; k < 10; ++k) {
            float m = Bm[k];
            #pragma unroll
            for (int j = 0; j < 10; ++j) m += Wa[k * 10 + j] * xi[j] + Wb[k * 10 + j] * xj[j];
            atomicAdd(po + k, m);
        }
    }
}

// ---------------- output: out = h @ w_out.T + b_out ------------------------
__global__ void k_out(const float* __restrict__ h, const float* __restrict__ w_out,
                      const float* __restrict__ b_out, float* __restrict__ out, int n) {
    __shared__ float W[100];
    __shared__ float B[10];
    int t = threadIdx.x;
    if (t < 100) W[t] = w_out[t];
    if (t < 10)  B[t] = b_out[t];
    __syncthreads();
    int gs = gridDim.x * blockDim.x;
    for (int i = blockIdx.x * blockDim.x + t; i < n; i += gs) {
        float xi[10];
        #pragma unroll
        for (int j = 0; j < 10; ++j) xi[j] = h[(size_t)i * 16 + j];
        #pragma unroll
        for (int k = 0; k < 10; ++k) {
            float m = B[k];
            #pragma unroll
            for (int j = 0; j < 10; ++j) m += W[k * 10 + j] * xi[j];
            out[(size_t)i * 10 + k] = m;
        }
    }
}

// =================== tiny-ws atomic fallback ================================

__global__ void k_init10(const float* __restrict__ x, float* __restrict__ h, int n10) {
    int gs = gridDim.x * blockDim.x;
    for (int i = blockIdx.x * blockDim.x + threadIdx.x; i < n10; i += gs) h[i] = x[i];
}
__global__ void k_copy4(const float4* __restrict__ src, float4* __restrict__ dst, int n4) {
    int gs = gridDim.x * blockDim.x;
    for (int i = blockIdx.x * blockDim.x + threadIdx.x; i < n4; i += gs) dst[i] = src[i];
}
__global__ void k_edge_step10(const float* __restrict__ h_cur, float* __restrict__ h_next,
                              const int* __restrict__ edge_index, const int* __restrict__ order,
                              const float* __restrict__ w_mp, const float* __restrict__ b_mp,
                              int epo, int ne) {
    __shared__ float Wc[200]; __shared__ float Bc[10];
    int t = threadIdx.x;
    if (t < 200) {
        int k = t / 20, j = t - k * 20;
        float w = w_mp[t];
        Wc[t] = (j < 10) ? (w - w_mp[k * 20 + j + 10]) : w;
    }
    if (t < 10) Bc[t] = b_mp[t];
    __syncthreads();
    int gs = gridDim.x * blockDim.x;
    for (int e = blockIdx.x * blockDim.x + t; e < epo; e += gs) {
        int idx = order[e];
        int dst = edge_index[idx];
        int src = edge_index[(size_t)ne + idx];
        const float* pi = h_cur + (size_t)dst * 10;
        const float* pj = h_cur + (size_t)src * 10;
        float xi[10], xj[10];
        #pragma unroll
        for (int j = 0; j < 10; ++j) { xi[j] = pi[j]; xj[j] = pj[j]; }
        float* po = h_next + (size_t)dst * 10;
        #pragma unroll
        for (int k = 0; k < 10; ++k) {
            float m = Bc[k];
            #pragma unroll
            for (int j = 0; j < 10; ++j) m += Wc[k * 20 + j] * xi[j] + Wc[k * 20 + 10 + j] * xj[j];
            atomicAdd(po + k, m);
        }
    }
}
__global__ void k_out10(const float* __restrict__ h, const float* __restrict__ w_out,
                        const float* __restrict__ b_out, float* __restrict__ out, int n) {
    __shared__ float W[100]; __shared__ float B[10];
    int t = threadIdx.x;
    if (t < 100) W[t] = w_out[t];
    if (t < 10)  B[t] = b_out[t];
    __syncthreads();
    int gs = gridDim.x * blockDim.x;
    for (int i = blockIdx.x * blockDim.x + t; i < n; i += gs) {
        float xi[10];
        #pragma unroll
        for (int j = 0; j < 10; ++j) xi[j] = h[(size_t)i * 10 + j];
        #pragma unroll
        for (int k = 0; k < 10; ++k) {
            float m = B[k];
            #pragma unroll
            for (int j = 0; j < 10; ++j) m += W[k * 10 + j] * xi[j];
            out[(size_t)i * 10 + k] = m;
        }
    }
}

// =================== launcher ===================

extern "C" void kernel_launch(void* const* d_in, const int* in_sizes, int n_in,
                              void* d_out, int out_size, void* d_ws, size_t ws_size,
                              hipStream_t stream) {
    const float* x      = (const float*)d_in[0];
    const float* w_mp   = (const float*)d_in[1];
    const float* b_mp   = (const float*)d_in[2];
    const float* w_out  = (const float*)d_in[3];
    const float* b_out  = (const float*)d_in[4];
    const int*   edge_i = (const int*)d_in[5];
    const int*   orders = (const int*)d_in[6];

    int n  = in_sizes[0] / 10;        // 100000
    int ne = in_sizes[5] / 2;         // 6400000
    const int n_orders = 4;
    int epo = in_sizes[6] / n_orders; // 1600000

    float* out = (float*)d_out;

    int NBI = (ne + 4095) >> 12;      // idx buckets (1563)
    int NBD = (n + 511) >> 9;         // dst buckets (196)
    int tps = (epo + TILE1 - 1) / TILE1;

    // workspace layout (elements)
    size_t off_hA    = 0;
    size_t off_hB    = off_hA + (size_t)n * 16;
    size_t off_recs1 = off_hB + (size_t)n * 16;
    size_t off_recs2 = off_recs1 + (size_t)4 * NBI * K1CAP;
    size_t off_ovf2  = off_recs2 + (size_t)4 * NBD * CAPB;       // int2: even 4B offset ok
    size_t off_ovf1  = off_ovf2 + (size_t)OVFN * 2;
    size_t off_gcnt1 = off_ovf1 + OVFN;
    size_t off_gcnt2 = off_gcnt1 + (size_t)4 * NBI;
    size_t off_cnts  = off_gcnt2 + (size_t)4 * NBD;              // 2 overflow counters
    size_t total_el  = off_cnts + 2;
    size_t need      = total_el * 4;

    bool ok = (ws_size >= need) && (NBI <= MAXNBI) && (4 * NBD <= MAXS2) &&
              (ne < (1 << 23)) && (n < (1 << 17)) && (epo == (in_sizes[6] / 4));

    if (!ok) {
        // tiny-ws atomic fallback (8 MB)
        float* hA = (float*)d_ws;
        float* hB = hA + (size_t)n * 10;
        int n10 = n * 10;
        hipLaunchKernelGGL(k_init10, dim3(min((n10 + BLK - 1) / BLK, 2048)), dim3(BLK), 0, stream,
                           x, hA, n10);
        int n4 = n10 / 4;
        float* cur = hA; float* nxt = hB;
        int gb_edge = min((epo + BLK - 1) / BLK, 6400);
        for (int s = 0; s < n_orders; ++s) {
            hipLaunchKernelGGL(k_copy4, dim3(min((n4 + BLK - 1) / BLK, 2048)), dim3(BLK), 0, stream,
                               (const float4*)cur, (float4*)nxt, n4);
            hipLaunchKernelGGL(k_edge_step10, dim3(gb_edge), dim3(BLK), 0, stream,
                               cur, nxt, edge_i, orders + (size_t)s * epo, w_mp, b_mp, epo, ne);
            float* t2 = cur; cur = nxt; nxt = t2;
        }
        hipLaunchKernelGGL(k_out10, dim3(min((n + BLK - 1) / BLK, 2048)), dim3(BLK), 0, stream,
                           cur, w_out, b_out, out, n);
        return;
    }

    float*    hA      = (float*)d_ws;
    float*    hB      = (float*)d_ws + off_hB;
    int*      recs1   = (int*)d_ws + off_recs1;
    unsigned* recs2   = (unsigned*)d_ws + off_recs2;
    int2*     ovf2    = (int2*)((int*)d_ws + off_ovf2);
    int*      ovf1    = (int*)d_ws + off_ovf1;
    int*      gcnt1   = (int*)d_ws + off_gcnt1;
    int*      gcnt2   = (int*)d_ws + off_gcnt2;
    int*      ovfcnts = (int*)d_ws + off_cnts;   // [0]=ovf1_cnt, [1]=ovf2_cnt

    // zero all counters in one memset (gcnt1, gcnt2, ovfcnts are contiguous)
    hipMemsetAsync(gcnt1, 0, ((size_t)4 * NBI + (size_t)4 * NBD + 2) * sizeof(int), stream);

    int gb_init = min((n * 16 + BLK - 1) / BLK, 2048);
    hipLaunchKernelGGL(k_init_h, dim3(gb_init), dim3(BLK), 0, stream, x, hA, n);

    hipLaunchKernelGGL(k_bin1, dim3(4 * tps), dim3(256), 0, stream,
                       orders, epo, NBI, tps, gcnt1, recs1, ovfcnts + 0, ovf1);

    hipLaunchKernelGGL(k_bin2, dim3(NBI), dim3(256), 0, stream,
                       edge_i, ne, gcnt1, recs1, NBI, NBD,
                       gcnt2, recs2, ovfcnts + 1, ovf2);

    float* cur = hA; float* nxt = hB;
    for (int s = 0; s < n_orders; ++s) {
        hipLaunchKernelGGL(k_agg, dim3(NBD * 2), dim3(256), 0, stream,
                           cur, nxt, gcnt2 + (size_t)s * NBD,
                           recs2 + (size_t)s * NBD * CAPB, w_mp, b_mp, n);
        hipLaunchKernelGGL(k_fix, dim3(8), dim3(256), 0, stream,
                           cur, nxt, edge_i, ovfcnts + 0 ? ne : ne,
                           ovfcnts + 0, ovf1, ovfcnts + 1, ovf2, w_mp, b_mp, s);
        float* t2 = cur; cur = nxt; nxt = t2;
    }

    hipLaunchKernelGGL(k_out, dim3(min((n + BLK - 1) / BLK, 2048)), dim3(BLK), 0, stream,
                       cur, w_out, b_out, out, n);
}

// Round 5
// 671.489 us; speedup vs baseline: 1.0140x; 1.0140x over previous
//
#include <hip/hip_runtime.h>

#define BLK 256
#define TILEB 4096        // records per bin block
#define IPTB 16           // records per thread in k_binD (256 thr)
#define CAPB 4608         // per-(step,bucket) stream cap: mean 4096, sd 64 (+8 sigma)
#define MAXNBD 512
#define OVFN 65536

// ---------------- init: copy compact x (n,10) into strided h (n,16) --------
__global__ void k_init_h(const float* __restrict__ x, float* __restrict__ h, int n) {
    int total = n * 16;
    int gs = gridDim.x * blockDim.x;
    for (int i = blockIdx.x * blockDim.x + threadIdx.x; i < total; i += gs) {
        int row = i >> 4, col = i & 15;
        h[i] = (col < 10) ? x[row * 10 + col] : 0.0f;
    }
}

// ---------------- optional: interleave edge_index into (d,s) pairs ---------
__global__ void k_pairs(const int* __restrict__ ei, int2* __restrict__ pairs, int ne) {
    int gs = gridDim.x * blockDim.x;
    for (int i = blockIdx.x * blockDim.x + threadIdx.x; i < ne; i += gs)
        pairs[i] = make_int2(ei[i], ei[(size_t)ne + i]);
}

// ---------------- single-pass bin by dst>>8 ---------------------------------
// recs2: [4][NBD][CAPB] of (dl<<20 | s); gcnt2: [4][NBD]
template<bool PAIRS>
__global__ __launch_bounds__(256) void k_binD(const int* __restrict__ ei,
                                              const int2* __restrict__ pairs, int ne,
                                              const int* __restrict__ orders, int epo,
                                              int tps, int NBD,
                                              int* __restrict__ gcnt2,
                                              unsigned* __restrict__ recs2,
                                              int* __restrict__ ovf_cnt,
                                              int2* __restrict__ ovf) {
    __shared__ int bcnt[MAXNBD];
    __shared__ int gbase[MAXNBD];
    int t = threadIdx.x;
    int st = blockIdx.x / tps;
    int tb = blockIdx.x % tps;
    for (int i = t; i < NBD; i += 256) bcnt[i] = 0;
    __syncthreads();

    int base = tb * TILEB;
    const int* ord = orders + (size_t)st * epo;

    int idxs[IPTB];
    #pragma unroll
    for (int q = 0; q < IPTB; ++q) {
        int e = base + q * 256 + t;
        idxs[q] = (e < epo) ? ord[e] : -1;
    }
    int dv[IPTB], sv[IPTB];
    #pragma unroll
    for (int q = 0; q < IPTB; ++q) {
        dv[q] = 0; sv[q] = 0;
        if (idxs[q] >= 0) {
            if (PAIRS) { int2 p = pairs[idxs[q]]; dv[q] = p.x; sv[q] = p.y; }
            else       { dv[q] = ei[idxs[q]]; sv[q] = ei[(size_t)ne + idxs[q]]; }
        }
    }
    unsigned rec[IPTB]; int meta[IPTB];
    #pragma unroll
    for (int q = 0; q < IPTB; ++q) {
        meta[q] = -1; rec[q] = 0u;
        if (idxs[q] >= 0) {
            int key = dv[q] >> 8;                         // < 512
            int rk = atomicAdd(&bcnt[key], 1);            // < TILEB = 4096
            rec[q] = ((unsigned)(dv[q] & 255) << 20) | (unsigned)sv[q];
            meta[q] = (key << 13) | rk;
        }
    }
    __syncthreads();
    for (int k = t; k < NBD; k += 256) {
        int c = bcnt[k];
        gbase[k] = c ? atomicAdd(&gcnt2[st * NBD + k], c) : 0;
    }
    __syncthreads();
    #pragma unroll
    for (int q = 0; q < IPTB; ++q) {
        if (meta[q] >= 0) {
            int key = meta[q] >> 13, rk = meta[q] & 8191;
            int pos = gbase[key] + rk;
            if (pos < CAPB) {
                recs2[((size_t)st * NBD + key) * CAPB + pos] = rec[q];
            } else {
                int o = atomicAdd(ovf_cnt, 1);
                if (o < OVFN) {
                    int d = key * 256 + (int)(rec[q] >> 20);
                    ovf[o] = make_int2((st << 18) | d, (int)(rec[q] & 0xFFFFFu));
                }
            }
        }
    }
}

// ---------------- aggregate one step: component-major LDS accumulators -----
// h_next[i] = h[i] + deg*(Wa.x_i + b) + Wb * sum_src x_src
__global__ __launch_bounds__(512) void k_agg(const float* __restrict__ h_cur,
                                             float* __restrict__ h_next,
                                             const int* __restrict__ gcnt2_st,
                                             const unsigned* __restrict__ recs2_st,
                                             const float* __restrict__ w_mp,
                                             const float* __restrict__ b_mp, int n) {
    __shared__ float acc[11 * 256];     // acc[j][node], j=10 is degree
    __shared__ float Wa[100], Wb[100], Bm[10];
    int t = threadIdx.x;
    if (t < 100) {
        int k = t / 10, j = t - k * 10;
        float w1 = w_mp[k * 20 + j];
        float w2 = w_mp[k * 20 + 10 + j];
        Wa[t] = w1 - w2; Wb[t] = w2;
    }
    if (t < 10) Bm[t] = b_mp[t];
    for (int i = t; i < 11 * 256; i += 512) acc[i] = 0.0f;
    __syncthreads();

    int bkt = blockIdx.x;
    int cnt = gcnt2_st[bkt];
    if (cnt > CAPB) cnt = CAPB;
    const unsigned* strm = recs2_st + (size_t)bkt * CAPB;

    for (int r = t; r < cnt; r += 512) {
        unsigned rec = strm[r];
        int dl = (int)(rec >> 20);
        int s  = (int)(rec & 0xFFFFFu);
        const float* pj = h_cur + (size_t)s * 16;
        float4 a0 = *(const float4*)(pj);
        float4 a1 = *(const float4*)(pj + 4);
        float2 a2 = *(const float2*)(pj + 8);
        atomicAdd(&acc[0 * 256 + dl], a0.x);
        atomicAdd(&acc[1 * 256 + dl], a0.y);
        atomicAdd(&acc[2 * 256 + dl], a0.z);
        atomicAdd(&acc[3 * 256 + dl], a0.w);
        atomicAdd(&acc[4 * 256 + dl], a1.x);
        atomicAdd(&acc[5 * 256 + dl], a1.y);
        atomicAdd(&acc[6 * 256 + dl], a1.z);
        atomicAdd(&acc[7 * 256 + dl], a1.w);
        atomicAdd(&acc[8 * 256 + dl], a2.x);
        atomicAdd(&acc[9 * 256 + dl], a2.y);
        atomicAdd(&acc[10 * 256 + dl], 1.0f);
    }
    __syncthreads();

    if (t < 256) {
        int i = bkt * 256 + t;
        if (i < n) {
            const float* pi = h_cur + (size_t)i * 16;
            float4 x0 = *(const float4*)(pi);
            float4 x1 = *(const float4*)(pi + 4);
            float2 x2 = *(const float2*)(pi + 8);
            float xi[10] = {x0.x, x0.y, x0.z, x0.w, x1.x, x1.y, x1.z, x1.w, x2.x, x2.y};
            float S[10];
            #pragma unroll
            for (int j = 0; j < 10; ++j) S[j] = acc[j * 256 + t];
            float deg = acc[10 * 256 + t];

            float o[10];
            #pragma unroll
            for (int k = 0; k < 10; ++k) {
                float ma = Bm[k];
                float mb = 0.0f;
                #pragma unroll
                for (int j = 0; j < 10; ++j) {
                    ma += Wa[k * 10 + j] * xi[j];
                    mb += Wb[k * 10 + j] * S[j];
                }
                o[k] = xi[k] + deg * ma + mb;
            }
            float* po = h_next + (size_t)i * 16;
            *(float4*)(po)     = make_float4(o[0], o[1], o[2], o[3]);
            *(float4*)(po + 4) = make_float4(o[4], o[5], o[6], o[7]);
            *(float2*)(po + 8) = make_float2(o[8], o[9]);
        }
    }
}

// ---------------- overflow fix-up (expected zero entries) -------------------
__global__ void k_fix(const float* __restrict__ h_cur, float* __restrict__ h_next,
                      const int* __restrict__ ovf_cnt, const int2* __restrict__ ovf,
                      const float* __restrict__ w_mp, const float* __restrict__ b_mp,
                      int st) {
    __shared__ float Wa[100], Wb[100], Bm[10];
    int t = threadIdx.x;
    if (t < 100) {
        int k = t / 10, j = t - k * 10;
        float w1 = w_mp[k * 20 + j];
        float w2 = w_mp[k * 20 + 10 + j];
        Wa[t] = w1 - w2; Wb[t] = w2;
    }
    if (t < 10) Bm[t] = b_mp[t];
    __syncthreads();
    int c = *ovf_cnt; if (c > OVFN) c = OVFN;
    int gs = gridDim.x * blockDim.x;
    for (int i = blockIdx.x * blockDim.x + t; i < c; i += gs) {
        int2 p = ovf[i];
        if ((p.x >> 18) != st) continue;
        int d = p.x & 0x3FFFF, s = p.y;
        const float* pi = h_cur + (size_t)d * 16;
        const float* pj = h_cur + (size_t)s * 16;
        float xi[10], xj[10];
        #pragma unroll
        for (int j = 0; j < 10; ++j) { xi[j] = pi[j]; xj[j] = pj[j]; }
        float* po = h_next + (size_t)d * 16;
        #pragma unroll
        for (int k = 0; k < 10; ++k) {
            float m = Bm[k];
            #pragma unroll
            for (int j = 0; j < 10; ++j) m += Wa[k * 10 + j] * xi[j] + Wb[k * 10 + j] * xj[j];
            atomicAdd(po + k, m);
        }
    }
}

// ---------------- output: out = h @ w_out.T + b_out ------------------------
__global__ void k_out(const float* __restrict__ h, const float* __restrict__ w_out,
                      const float* __restrict__ b_out, float* __restrict__ out, int n) {
    __shared__ float W[100];
    __shared__ float B[10];
    int t = threadIdx.x;
    if (t < 100) W[t] = w_out[t];
    if (t < 10)  B[t] = b_out[t];
    __syncthreads();
    int gs = gridDim.x * blockDim.x;
    for (int i = blockIdx.x * blockDim.x + t; i < n; i += gs) {
        float xi[10];
        #pragma unroll
        for (int j = 0; j < 10; ++j) xi[j] = h[(size_t)i * 16 + j];
        #pragma unroll
        for (int k = 0; k < 10; ++k) {
            float m = B[k];
            #pragma unroll
            for (int j = 0; j < 10; ++j) m += W[k * 10 + j] * xi[j];
            out[(size_t)i * 10 + k] = m;
        }
    }
}

// =================== tiny-ws atomic fallback ================================

__global__ void k_init10(const float* __restrict__ x, float* __restrict__ h, int n10) {
    int gs = gridDim.x * blockDim.x;
    for (int i = blockIdx.x * blockDim.x + threadIdx.x; i < n10; i += gs) h[i] = x[i];
}
__global__ void k_copy4(const float4* __restrict__ src, float4* __restrict__ dst, int n4) {
    int gs = gridDim.x * blockDim.x;
    for (int i = blockIdx.x * blockDim.x + threadIdx.x; i < n4; i += gs) dst[i] = src[i];
}
__global__ void k_edge_step10(const float* __restrict__ h_cur, float* __restrict__ h_next,
                              const int* __restrict__ edge_index, const int* __restrict__ order,
                              const float* __restrict__ w_mp, const float* __restrict__ b_mp,
                              int epo, int ne) {
    __shared__ float Wc[200]; __shared__ float Bc[10];
    int t = threadIdx.x;
    if (t < 200) {
        int k = t / 20, j = t - k * 20;
        float w = w_mp[t];
        Wc[t] = (j < 10) ? (w - w_mp[k * 20 + j + 10]) : w;
    }
    if (t < 10) Bc[t] = b_mp[t];
    __syncthreads();
    int gs = gridDim.x * blockDim.x;
    for (int e = blockIdx.x * blockDim.x + t; e < epo; e += gs) {
        int idx = order[e];
        int dst = edge_index[idx];
        int src = edge_index[(size_t)ne + idx];
        const float* pi = h_cur + (size_t)dst * 10;
        const float* pj = h_cur + (size_t)src * 10;
        float xi[10], xj[10];
        #pragma unroll
        for (int j = 0; j < 10; ++j) { xi[j] = pi[j]; xj[j] = pj[j]; }
        float* po = h_next + (size_t)dst * 10;
        #pragma unroll
        for (int k = 0; k < 10; ++k) {
            float m = Bc[k];
            #pragma unroll
            for (int j = 0; j < 10; ++j) m += Wc[k * 20 + j] * xi[j] + Wc[k * 20 + 10 + j] * xj[j];
            atomicAdd(po + k, m);
        }
    }
}
__global__ void k_out10(const float* __restrict__ h, const float* __restrict__ w_out,
                        const float* __restrict__ b_out, float* __restrict__ out, int n) {
    __shared__ float W[100]; __shared__ float B[10];
    int t = threadIdx.x;
    if (t < 100) W[t] = w_out[t];
    if (t < 10)  B[t] = b_out[t];
    __syncthreads();
    int gs = gridDim.x * blockDim.x;
    for (int i = blockIdx.x * blockDim.x + t; i < n; i += gs) {
        float xi[10];
        #pragma unroll
        for (int j = 0; j < 10; ++j) xi[j] = h[(size_t)i * 10 + j];
        #pragma unroll
        for (int k = 0; k < 10; ++k) {
            float m = B[k];
            #pragma unroll
            for (int j = 0; j < 10; ++j) m += W[k * 10 + j] * xi[j];
            out[(size_t)i * 10 + k] = m;
        }
    }
}

// =================== launcher ===================

extern "C" void kernel_launch(void* const* d_in, const int* in_sizes, int n_in,
                              void* d_out, int out_size, void* d_ws, size_t ws_size,
                              hipStream_t stream) {
    const float* x      = (const float*)d_in[0];
    const float* w_mp   = (const float*)d_in[1];
    const float* b_mp   = (const float*)d_in[2];
    const float* w_out  = (const float*)d_in[3];
    const float* b_out  = (const float*)d_in[4];
    const int*   edge_i = (const int*)d_in[5];
    const int*   orders = (const int*)d_in[6];

    int n  = in_sizes[0] / 10;        // 100000
    int ne = in_sizes[5] / 2;         // 6400000
    const int n_orders = 4;
    int epo = in_sizes[6] / n_orders; // 1600000

    float* out = (float*)d_out;

    int NBD = (n + 255) >> 8;                    // 391 dst buckets
    int tps = (epo + TILEB - 1) / TILEB;         // 391 tiles per step

    // workspace layout (4B elements)
    size_t off_hA    = 0;
    size_t off_hB    = off_hA + (size_t)n * 16;
    size_t off_recs2 = off_hB + (size_t)n * 16;
    size_t off_ovf   = off_recs2 + (size_t)4 * NBD * CAPB;  // even
    size_t off_gcnt2 = off_ovf + (size_t)2 * OVFN;
    size_t off_cnt   = off_gcnt2 + (size_t)4 * NBD;
    size_t off_pairs = (off_cnt + 2) & ~(size_t)1;          // 8B aligned
    size_t need_base  = (off_cnt + 1) * 4;
    size_t need_pairs = (off_pairs + (size_t)2 * ne) * 4;

    bool ok = (ws_size >= need_base) && (NBD <= MAXNBD) && (n < (1 << 17));

    if (!ok) {
        // tiny-ws atomic fallback (8 MB)
        float* hA = (float*)d_ws;
        float* hB = hA + (size_t)n * 10;
        int n10 = n * 10;
        hipLaunchKernelGGL(k_init10, dim3(min((n10 + BLK - 1) / BLK, 2048)), dim3(BLK), 0, stream,
                           x, hA, n10);
        int n4 = n10 / 4;
        float* cur = hA; float* nxt = hB;
        int gb_edge = min((epo + BLK - 1) / BLK, 6400);
        for (int s = 0; s < n_orders; ++s) {
            hipLaunchKernelGGL(k_copy4, dim3(min((n4 + BLK - 1) / BLK, 2048)), dim3(BLK), 0, stream,
                               (const float4*)cur, (float4*)nxt, n4);
            hipLaunchKernelGGL(k_edge_step10, dim3(gb_edge), dim3(BLK), 0, stream,
                               cur, nxt, edge_i, orders + (size_t)s * epo, w_mp, b_mp, epo, ne);
            float* t2 = cur; cur = nxt; nxt = t2;
        }
        hipLaunchKernelGGL(k_out10, dim3(min((n + BLK - 1) / BLK, 2048)), dim3(BLK), 0, stream,
                           cur, w_out, b_out, out, n);
        return;
    }

    float*    hA      = (float*)d_ws;
    float*    hB      = (float*)d_ws + off_hB;
    unsigned* recs2   = (unsigned*)d_ws + off_recs2;
    int2*     ovf     = (int2*)((int*)d_ws + off_ovf);
    int*      gcnt2   = (int*)d_ws + off_gcnt2;
    int*      ovf_cnt = (int*)d_ws + off_cnt;
    bool use_pairs = (ws_size >= need_pairs);
    int2* pairs = use_pairs ? (int2*)((int*)d_ws + off_pairs) : nullptr;

    // zero gcnt2 + ovf_cnt (contiguous)
    hipMemsetAsync(gcnt2, 0, ((size_t)4 * NBD + 1) * sizeof(int), stream);

    int gb_init = min((n * 16 + BLK - 1) / BLK, 2048);
    hipLaunchKernelGGL(k_init_h, dim3(gb_init), dim3(BLK), 0, stream, x, hA, n);

    if (use_pairs) {
        int gb_p = min((ne + BLK - 1) / BLK, 4096);
        hipLaunchKernelGGL(k_pairs, dim3(gb_p), dim3(BLK), 0, stream, edge_i, pairs, ne);
        hipLaunchKernelGGL((k_binD<true>), dim3(4 * tps), dim3(256), 0, stream,
                           edge_i, pairs, ne, orders, epo, tps, NBD,
                           gcnt2, recs2, ovf_cnt, ovf);
    } else {
        hipLaunchKernelGGL((k_binD<false>), dim3(4 * tps), dim3(256), 0, stream,
                           edge_i, nullptr, ne, orders, epo, tps, NBD,
                           gcnt2, recs2, ovf_cnt, ovf);
    }

    float* cur = hA; float* nxt = hB;
    for (int s = 0; s < n_orders; ++s) {
        hipLaunchKernelGGL(k_agg, dim3(NBD), dim3(512), 0, stream,
                           cur, nxt, gcnt2 + (size_t)s * NBD,
                           recs2 + (size_t)s * NBD * CAPB, w_mp, b_mp, n);
        hipLaunchKernelGGL(k_fix, dim3(8), dim3(256), 0, stream,
                           cur, nxt, ovf_cnt, ovf, w_mp, b_mp, s);
        float* t2 = cur; cur = nxt; nxt = t2;
    }

    hipLaunchKernelGGL(k_out, dim3(min((n + BLK - 1) / BLK, 2048)), dim3(BLK), 0, stream,
                       cur, w_out, b_out, out, n);
}

// Round 6
// 294.520 us; speedup vs baseline: 2.3120x; 2.2799x over previous
//
#include <hip/hip_runtime.h>

#define BLK 256
#define TILEB 4096        // records per bin block
#define IPTB 16           // records per thread in k_binD (256 thr)
#define CAPB 4608         // per-(step,bucket) stream cap: mean 4096, sd 64 (+8 sigma)
#define MAXNBD 512
#define OVFN 65536

// ---------------- init: copy compact x (n,10) into strided h (n,16) --------
__global__ void k_init_h(const float* __restrict__ x, float* __restrict__ h, int n) {
    int total = n * 16;
    int gs = gridDim.x * blockDim.x;
    for (int i = blockIdx.x * blockDim.x + threadIdx.x; i < total; i += gs) {
        int row = i >> 4, col = i & 15;
        h[i] = (col < 10) ? x[row * 10 + col] : 0.0f;
    }
}

// ---------------- interleave edge_index into (d,s) pairs -------------------
__global__ void k_pairs(const int* __restrict__ ei, int2* __restrict__ pairs, int ne) {
    int gs = gridDim.x * blockDim.x;
    for (int i = blockIdx.x * blockDim.x + threadIdx.x; i < ne; i += gs)
        pairs[i] = make_int2(ei[i], ei[(size_t)ne + i]);
}

// ---------------- single-pass bin by (step, dst>>8) ------------------------
// recs2: [4][NBD][CAPB] of (dl<<20 | s); gcnt2: [4][NBD]
template<bool PAIRS>
__global__ __launch_bounds__(256) void k_binD(const int* __restrict__ ei,
                                              const int2* __restrict__ pairs, int ne,
                                              const int* __restrict__ orders, int epo,
                                              int tps, int NBD,
                                              int* __restrict__ gcnt2,
                                              unsigned* __restrict__ recs2,
                                              int* __restrict__ ovf_cnt,
                                              int2* __restrict__ ovf) {
    __shared__ int bcnt[MAXNBD];
    __shared__ int gbase[MAXNBD];
    int t = threadIdx.x;
    int st = blockIdx.x / tps;
    int tb = blockIdx.x % tps;
    for (int i = t; i < NBD; i += 256) bcnt[i] = 0;
    __syncthreads();

    int base = tb * TILEB;
    const int* ord = orders + (size_t)st * epo;

    int idxs[IPTB];
    #pragma unroll
    for (int q = 0; q < IPTB; ++q) {
        int e = base + q * 256 + t;
        idxs[q] = (e < epo) ? ord[e] : -1;
    }
    int dv[IPTB], sv[IPTB];
    #pragma unroll
    for (int q = 0; q < IPTB; ++q) {
        dv[q] = 0; sv[q] = 0;
        if (idxs[q] >= 0) {
            if (PAIRS) { int2 p = pairs[idxs[q]]; dv[q] = p.x; sv[q] = p.y; }
            else       { dv[q] = ei[idxs[q]]; sv[q] = ei[(size_t)ne + idxs[q]]; }
        }
    }
    unsigned rec[IPTB]; int meta[IPTB];
    #pragma unroll
    for (int q = 0; q < IPTB; ++q) {
        meta[q] = -1; rec[q] = 0u;
        if (idxs[q] >= 0) {
            int key = dv[q] >> 8;                         // < 512
            int rk = atomicAdd(&bcnt[key], 1);            // < TILEB = 4096
            rec[q] = ((unsigned)(dv[q] & 255) << 20) | (unsigned)sv[q];
            meta[q] = (key << 13) | rk;
        }
    }
    __syncthreads();
    for (int k = t; k < NBD; k += 256) {
        int c = bcnt[k];
        gbase[k] = c ? atomicAdd(&gcnt2[st * NBD + k], c) : 0;
    }
    __syncthreads();
    #pragma unroll
    for (int q = 0; q < IPTB; ++q) {
        if (meta[q] >= 0) {
            int key = meta[q] >> 13, rk = meta[q] & 8191;
            int pos = gbase[key] + rk;
            if (pos < CAPB) {
                recs2[((size_t)st * NBD + key) * CAPB + pos] = rec[q];
            } else {
                int o = atomicAdd(ovf_cnt, 1);
                if (o < OVFN) {
                    int d = key * 256 + (int)(rec[q] >> 20);
                    ovf[o] = make_int2((st << 18) | d, (int)(rec[q] & 0xFFFFFu));
                }
            }
        }
    }
}

// ---------------- aggregate via in-LDS counting sort, register sums --------
// h_next[i] = h[i] + deg*(Wa.x_i + b) + Wb * sum_src x_src  ; NO fp atomics
__global__ __launch_bounds__(512) void k_agg2(const float* __restrict__ h_cur,
                                              float* __restrict__ h_next,
                                              const int* __restrict__ gcnt2_st,
                                              const unsigned* __restrict__ recs2_st,
                                              const float* __restrict__ w_mp,
                                              const float* __restrict__ b_mp, int n) {
    __shared__ unsigned srt[CAPB];      // records sorted by dl
    __shared__ int cnts[256];           // histogram, then cursor
    __shared__ int sc[256];             // scan scratch
    __shared__ int offs[257];           // exclusive offsets
    __shared__ float part[256 * 10];    // partner partial sums
    __shared__ float Wa[100], Wb[100], Bm[10];
    int t = threadIdx.x;
    if (t < 100) {
        int k = t / 10, j = t - k * 10;
        float w1 = w_mp[k * 20 + j];
        float w2 = w_mp[k * 20 + 10 + j];
        Wa[t] = w1 - w2; Wb[t] = w2;
    }
    if (t < 10) Bm[t] = b_mp[t];
    if (t < 256) cnts[t] = 0;
    __syncthreads();

    int bkt = blockIdx.x;
    int cnt = gcnt2_st[bkt];
    if (cnt > CAPB) cnt = CAPB;
    const unsigned* strm = recs2_st + (size_t)bkt * CAPB;

    // pass A: stage to registers + histogram
    unsigned myrec[(CAPB + 511) / 512];
    int nm = 0;
    for (int r = t; r < cnt; r += 512) {
        unsigned rec = strm[r];
        myrec[nm++] = rec;
        atomicAdd(&cnts[rec >> 20], 1);
    }
    __syncthreads();

    // exclusive scan of cnts -> offs
    if (t < 256) sc[t] = cnts[t];
    __syncthreads();
    for (int off = 1; off < 256; off <<= 1) {
        int v = (t < 256 && t >= off) ? sc[t - off] : 0;
        __syncthreads();
        if (t < 256) sc[t] += v;
        __syncthreads();
    }
    if (t < 256) offs[t + 1] = sc[t];
    if (t == 0) offs[0] = 0;
    __syncthreads();
    if (t < 256) cnts[t] = offs[t];     // cursor
    __syncthreads();

    // pass B: scatter into sorted order
    for (int q = 0; q < nm; ++q) {
        unsigned rec = myrec[q];
        int pos = atomicAdd(&cnts[rec >> 20], 1);
        srt[pos] = rec;
    }
    __syncthreads();

    // per-node gather-sum: 2 threads per node
    int node = t & 255, half = t >> 8;
    int b0 = offs[node], m = offs[node + 1] - b0;
    float S[10] = {0,0,0,0,0,0,0,0,0,0};
    for (int p = b0 + half; p < b0 + m; p += 2) {
        int s = (int)(srt[p] & 0xFFFFFu);
        const float* pj = h_cur + (size_t)s * 16;
        float4 a0 = *(const float4*)(pj);
        float4 a1 = *(const float4*)(pj + 4);
        float2 a2 = *(const float2*)(pj + 8);
        S[0] += a0.x; S[1] += a0.y; S[2] += a0.z; S[3] += a0.w;
        S[4] += a1.x; S[5] += a1.y; S[6] += a1.z; S[7] += a1.w;
        S[8] += a2.x; S[9] += a2.y;
    }
    if (half == 1) {
        #pragma unroll
        for (int j = 0; j < 10; ++j) part[node * 10 + j] = S[j];
    }
    __syncthreads();
    if (half == 0) {
        int i = bkt * 256 + node;
        if (i < n) {
            #pragma unroll
            for (int j = 0; j < 10; ++j) S[j] += part[node * 10 + j];
            const float* pi = h_cur + (size_t)i * 16;
            float4 x0 = *(const float4*)(pi);
            float4 x1 = *(const float4*)(pi + 4);
            float2 x2 = *(const float2*)(pi + 8);
            float xi[10] = {x0.x, x0.y, x0.z, x0.w, x1.x, x1.y, x1.z, x1.w, x2.x, x2.y};
            float deg = (float)m;
            float o[10];
            #pragma unroll
            for (int k = 0; k < 10; ++k) {
                float ma = Bm[k];
                float mb = 0.0f;
                #pragma unroll
                for (int j = 0; j < 10; ++j) {
                    ma += Wa[k * 10 + j] * xi[j];
                    mb += Wb[k * 10 + j] * S[j];
                }
                o[k] = xi[k] + deg * ma + mb;
            }
            float* po = h_next + (size_t)i * 16;
            *(float4*)(po)     = make_float4(o[0], o[1], o[2], o[3]);
            *(float4*)(po + 4) = make_float4(o[4], o[5], o[6], o[7]);
            *(float2*)(po + 8) = make_float2(o[8], o[9]);
        }
    }
}

// ---------------- overflow fix-up (expected zero entries) -------------------
__global__ void k_fix(const float* __restrict__ h_cur, float* __restrict__ h_next,
                      const int* __restrict__ ovf_cnt, const int2* __restrict__ ovf,
                      const float* __restrict__ w_mp, const float* __restrict__ b_mp,
                      int st) {
    __shared__ float Wa[100], Wb[100], Bm[10];
    int t = threadIdx.x;
    if (t < 100) {
        int k = t / 10, j = t - k * 10;
        float w1 = w_mp[k * 20 + j];
        float w2 = w_mp[k * 20 + 10 + j];
        Wa[t] = w1 - w2; Wb[t] = w2;
    }
    if (t < 10) Bm[t] = b_mp[t];
    __syncthreads();
    int c = *ovf_cnt; if (c > OVFN) c = OVFN;
    int gs = gridDim.x * blockDim.x;
    for (int i = blockIdx.x * blockDim.x + t; i < c; i += gs) {
        int2 p = ovf[i];
        if ((p.x >> 18) != st) continue;
        int d = p.x & 0x3FFFF, s = p.y;
        const float* pi = h_cur + (size_t)d * 16;
        const float* pj = h_cur + (size_t)s * 16;
        float xi[10], xj[10];
        #pragma unroll
        for (int j = 0; j < 10; ++j) { xi[j] = pi[j]; xj[j] = pj[j]; }
        float* po = h_next + (size_t)d * 16;
        #pragma unroll
        for (int k = 0; k < 10; ++k) {
            float m = Bm[k];
            #pragma unroll
            for (int j = 0; j < 10; ++j) m += Wa[k * 10 + j] * xi[j] + Wb[k * 10 + j] * xj[j];
            atomicAdd(po + k, m);
        }
    }
}

// ---------------- output: out = h @ w_out.T + b_out ------------------------
__global__ void k_out(const float* __restrict__ h, const float* __restrict__ w_out,
                      const float* __restrict__ b_out, float* __restrict__ out, int n) {
    __shared__ float W[100];
    __shared__ float B[10];
    int t = threadIdx.x;
    if (t < 100) W[t] = w_out[t];
    if (t < 10)  B[t] = b_out[t];
    __syncthreads();
    int gs = gridDim.x * blockDim.x;
    for (int i = blockIdx.x * blockDim.x + t; i < n; i += gs) {
        float xi[10];
        #pragma unroll
        for (int j = 0; j < 10; ++j) xi[j] = h[(size_t)i * 16 + j];
        #pragma unroll
        for (int k = 0; k < 10; ++k) {
            float m = B[k];
            #pragma unroll
            for (int j = 0; j < 10; ++j) m += W[k * 10 + j] * xi[j];
            out[(size_t)i * 10 + k] = m;
        }
    }
}

// =================== tiny-ws atomic fallback ================================

__global__ void k_init10(const float* __restrict__ x, float* __restrict__ h, int n10) {
    int gs = gridDim.x * blockDim.x;
    for (int i = blockIdx.x * blockDim.x + threadIdx.x; i < n10; i += gs) h[i] = x[i];
}
__global__ void k_copy4(const float4* __restrict__ src, float4* __restrict__ dst, int n4) {
    int gs = gridDim.x * blockDim.x;
    for (int i = blockIdx.x * blockDim.x + threadIdx.x; i < n4; i += gs) dst[i] = src[i];
}
__global__ void k_edge_step10(const float* __restrict__ h_cur, float* __restrict__ h_next,
                              const int* __restrict__ edge_index, const int* __restrict__ order,
                              const float* __restrict__ w_mp, const float* __restrict__ b_mp,
                              int epo, int ne) {
    __shared__ float Wc[200]; __shared__ float Bc[10];
    int t = threadIdx.x;
    if (t < 200) {
        int k = t / 20, j = t - k * 20;
        float w = w_mp[t];
        Wc[t] = (j < 10) ? (w - w_mp[k * 20 + j + 10]) : w;
    }
    if (t < 10) Bc[t] = b_mp[t];
    __syncthreads();
    int gs = gridDim.x * blockDim.x;
    for (int e = blockIdx.x * blockDim.x + t; e < epo; e += gs) {
        int idx = order[e];
        int dst = edge_index[idx];
        int src = edge_index[(size_t)ne + idx];
        const float* pi = h_cur + (size_t)dst * 10;
        const float* pj = h_cur + (size_t)src * 10;
        float xi[10], xj[10];
        #pragma unroll
        for (int j = 0; j < 10; ++j) { xi[j] = pi[j]; xj[j] = pj[j]; }
        float* po = h_next + (size_t)dst * 10;
        #pragma unroll
        for (int k = 0; k < 10; ++k) {
            float m = Bc[k];
            #pragma unroll
            for (int j = 0; j < 10; ++j) m += Wc[k * 20 + j] * xi[j] + Wc[k * 20 + 10 + j] * xj[j];
            atomicAdd(po + k, m);
        }
    }
}
__global__ void k_out10(const float* __restrict__ h, const float* __restrict__ w_out,
                        const float* __restrict__ b_out, float* __restrict__ out, int n) {
    __shared__ float W[100]; __shared__ float B[10];
    int t = threadIdx.x;
    if (t < 100) W[t] = w_out[t];
    if (t < 10)  B[t] = b_out[t];
    __syncthreads();
    int gs = gridDim.x * blockDim.x;
    for (int i = blockIdx.x * blockDim.x + t; i < n; i += gs) {
        float xi[10];
        #pragma unroll
        for (int j = 0; j < 10; ++j) xi[j] = h[(size_t)i * 10 + j];
        #pragma unroll
        for (int k = 0; k < 10; ++k) {
            float m = B[k];
            #pragma unroll
            for (int j = 0; j < 10; ++j) m += W[k * 10 + j] * xi[j];
            out[(size_t)i * 10 + k] = m;
        }
    }
}

// =================== launcher ===================

extern "C" void kernel_launch(void* const* d_in, const int* in_sizes, int n_in,
                              void* d_out, int out_size, void* d_ws, size_t ws_size,
                              hipStream_t stream) {
    const float* x      = (const float*)d_in[0];
    const float* w_mp   = (const float*)d_in[1];
    const float* b_mp   = (const float*)d_in[2];
    const float* w_out  = (const float*)d_in[3];
    const float* b_out  = (const float*)d_in[4];
    const int*   edge_i = (const int*)d_in[5];
    const int*   orders = (const int*)d_in[6];

    int n  = in_sizes[0] / 10;        // 100000
    int ne = in_sizes[5] / 2;         // 6400000
    const int n_orders = 4;
    int epo = in_sizes[6] / n_orders; // 1600000

    float* out = (float*)d_out;

    int NBD = (n + 255) >> 8;                    // 391 dst buckets
    int tps = (epo + TILEB - 1) / TILEB;         // 391 tiles per step

    // workspace layout (4B elements)
    size_t off_hA    = 0;
    size_t off_hB    = off_hA + (size_t)n * 16;
    size_t off_recs2 = off_hB + (size_t)n * 16;
    size_t off_ovf   = off_recs2 + (size_t)4 * NBD * CAPB;  // even
    size_t off_gcnt2 = off_ovf + (size_t)2 * OVFN;
    size_t off_cnt   = off_gcnt2 + (size_t)4 * NBD;
    size_t off_pairs = (off_cnt + 2) & ~(size_t)1;          // 8B aligned
    size_t need_base  = (off_cnt + 1) * 4;
    size_t need_pairs = (off_pairs + (size_t)2 * ne) * 4;

    bool ok = (ws_size >= need_base) && (NBD <= MAXNBD) && (n < (1 << 17));

    if (!ok) {
        // tiny-ws atomic fallback (8 MB)
        float* hA = (float*)d_ws;
        float* hB = hA + (size_t)n * 10;
        int n10 = n * 10;
        hipLaunchKernelGGL(k_init10, dim3(min((n10 + BLK - 1) / BLK, 2048)), dim3(BLK), 0, stream,
                           x, hA, n10);
        int n4 = n10 / 4;
        float* cur = hA; float* nxt = hB;
        int gb_edge = min((epo + BLK - 1) / BLK, 6400);
        for (int s = 0; s < n_orders; ++s) {
            hipLaunchKernelGGL(k_copy4, dim3(min((n4 + BLK - 1) / BLK, 2048)), dim3(BLK), 0, stream,
                               (const float4*)cur, (float4*)nxt, n4);
            hipLaunchKernelGGL(k_edge_step10, dim3(gb_edge), dim3(BLK), 0, stream,
                               cur, nxt, edge_i, orders + (size_t)s * epo, w_mp, b_mp, epo, ne);
            float* t2 = cur; cur = nxt; nxt = t2;
        }
        hipLaunchKernelGGL(k_out10, dim3(min((n + BLK - 1) / BLK, 2048)), dim3(BLK), 0, stream,
                           cur, w_out, b_out, out, n);
        return;
    }

    float*    hA      = (float*)d_ws;
    float*    hB      = (float*)d_ws + off_hB;
    unsigned* recs2   = (unsigned*)d_ws + off_recs2;
    int2*     ovf     = (int2*)((int*)d_ws + off_ovf);
    int*      gcnt2   = (int*)d_ws + off_gcnt2;
    int*      ovf_cnt = (int*)d_ws + off_cnt;
    bool use_pairs = (ws_size >= need_pairs);
    int2* pairs = use_pairs ? (int2*)((int*)d_ws + off_pairs) : nullptr;

    // zero gcnt2 + ovf_cnt (contiguous)
    hipMemsetAsync(gcnt2, 0, ((size_t)4 * NBD + 1) * sizeof(int), stream);

    int gb_init = min((n * 16 + BLK - 1) / BLK, 2048);
    hipLaunchKernelGGL(k_init_h, dim3(gb_init), dim3(BLK), 0, stream, x, hA, n);

    if (use_pairs) {
        int gb_p = min((ne + BLK - 1) / BLK, 4096);
        hipLaunchKernelGGL(k_pairs, dim3(gb_p), dim3(BLK), 0, stream, edge_i, pairs, ne);
        hipLaunchKernelGGL((k_binD<true>), dim3(4 * tps), dim3(256), 0, stream,
                           edge_i, pairs, ne, orders, epo, tps, NBD,
                           gcnt2, recs2, ovf_cnt, ovf);
    } else {
        hipLaunchKernelGGL((k_binD<false>), dim3(4 * tps), dim3(256), 0, stream,
                           edge_i, nullptr, ne, orders, epo, tps, NBD,
                           gcnt2, recs2, ovf_cnt, ovf);
    }

    float* cur = hA; float* nxt = hB;
    for (int s = 0; s < n_orders; ++s) {
        hipLaunchKernelGGL(k_agg2, dim3(NBD), dim3(512), 0, stream,
                           cur, nxt, gcnt2 + (size_t)s * NBD,
                           recs2 + (size_t)s * NBD * CAPB, w_mp, b_mp, n);
        hipLaunchKernelGGL(k_fix, dim3(8), dim3(256), 0, stream,
                           cur, nxt, ovf_cnt, ovf, w_mp, b_mp, s);
        float* t2 = cur; cur = nxt; nxt = t2;
    }

    hipLaunchKernelGGL(k_out, dim3(min((n + BLK - 1) / BLK, 2048)), dim3(BLK), 0, stream,
                       cur, w_out, b_out, out, n);
}